// Round 9
// baseline (127.108 us; speedup 1.0000x reference)
//
#include <hip/hip_runtime.h>
#include <utility>

// EquivariantProductBasisBlock (MACE-style) for gfx950 — round 9.
// Plateau (~43us) invariant to occupancy/L2/VMEM-count/load-scheduling across
// R2-R8 -> limiter = instruction stream: ~24KB straight-line basis code, no
// reuse, streams from L2 every wave-pass. R9: (1) packed fp32 (v2f +
// __builtin_elementwise_fma -> v_pk_fma_f32): 2 channels/thread, same inst
// count, 2x work; (2) split basis/linear kernels (linear = small looped code,
// B via d_ws). Weights loaded at use as float2 (no big live arrays - R5
// lesson), no VGPR caps (R4 lesson).

#define NN 4096
#define NC 128
#define NE 10

typedef float v2f __attribute__((ext_vector_type(2)));

__device__ __forceinline__ v2f ld2(const float* p) {
  return *reinterpret_cast<const v2f*>(p);
}
__device__ __forceinline__ v2f cfma(float c, v2f x, v2f a) {  // a += c*x (splat c)
  v2f cc = {c, c};
  return __builtin_elementwise_fma(cc, x, a);
}
__device__ __forceinline__ v2f vfma(v2f w, v2f x, v2f a) {    // a += w*x
  return __builtin_elementwise_fma(w, x, a);
}

// ---------------------------- static_for ---------------------------------------
template<typename F, int... Is>
__device__ __forceinline__ void sfor_impl(F&& f, std::integer_sequence<int, Is...>) {
  (f(std::integral_constant<int, Is>{}), ...);
}
template<int N, typename F>
__device__ __forceinline__ void sfor(F&& f) {
  sfor_impl((F&&)f, std::make_integer_sequence<int, N>{});
}

// ---------------------------- CG metadata (constexpr) --------------------------
constexpr int T_L1c[19]  = {0,0,0,1,1,1,1,1,1,1,2,2,2,2,2,2,2,2,3};
constexpr int T_L2c[19]  = {0,1,2,0,1,1,1,2,2,2,0,1,1,1,2,2,2,2,2};
constexpr int T_L3c[19]  = {0,1,2,1,0,1,2,1,2,3,2,1,2,3,0,1,2,3,1};
constexpr int T_OFFc[19] = {0,1,10,35,44,53,80,125,170,245,350,375,420,495,600,625,700,825,1000};
constexpr int AOFFc[3]   = {0,1,4};

// order-2 unique paths after exchange-merging (verified by static_assert)
constexpr int P2U_L1c[7]  = {0,0,1,1,1,2,2};
constexpr int P2U_L2c[7]  = {0,1,1,1,2,2,2};
constexpr int P2U_LOc[7]  = {0,1,0,1,1,0,1};
constexpr int P2U_TBLc[7] = {0,1,4,5,7,14,15};
constexpr int P2U_WAc[7]  = {0,1,3,4,5,7,8};
constexpr int P2U_WBc[7]  = {-1,2,-1,-1,6,-1,-1};

constexpr int K_L1c[18]  = {0,0,0,1,1,1,1,1,1,1,2,2,2,2,2,2,2,2};
constexpr int K_L2c[18]  = {0,1,2,0,1,1,1,2,2,2,0,1,1,1,2,2,2,2};
constexpr int K_L12c[18] = {0,1,2,1,0,1,2,1,2,3,2,1,2,3,0,1,2,3};

constexpr int   TT_CANONc[18] = {0,1,2,1,4,5,6,7,8,9,2,7,8,9,14,15,16,17};
constexpr float TT_SGNc[18]   = {1,1,1,1,1,1,1,1,1,1,1,1,-1,1,1,1,1,1};
constexpr int CANONc[13] = {0,1,2,4,5,6,7,8,9,14,15,16,17};
constexpr int CONS2c[13] = {-1,3,10,-1,-1,-1,11,12,13,-1,-1,-1,-1};

constexpr int P3_STARTc[19] = {0,2,6,9,13,15,19,22,26,29,30,33,37,40,41,43,47,50,51};
constexpr int P3_L3c[51] = {
  0,1,  0,1,1,2,  1,2,2,  0,1,1,2,  0,1,  0,1,1,2,  1,2,2,  0,1,1,2,  1,2,2,
  2,  1,2,2,  0,1,1,2,  1,2,2,  2,  0,1,  0,1,1,2,  1,2,2,  2 };
constexpr int P3_LOc[51] = {
  0,1,  1,0,1,1,  1,0,1,  1,0,1,1,  0,1,  1,0,1,1,  1,0,1,  1,0,1,1,  1,0,1,
  1,  1,0,1,  1,0,1,1,  1,0,1,  1,  0,1,  1,0,1,1,  1,0,1,  1 };
constexpr int P3_TBLc[51] = {
  0,1,  3,4,5,7,  11,14,15,  3,4,5,7,  0,1,  3,4,5,7,  11,14,15,  3,4,5,7,
  11,14,15,  18,  11,14,15,  3,4,5,7,  11,14,15,  18,  0,1,  3,4,5,7,
  11,14,15,  18 };

// ---------------------------- constexpr CG computation -------------------------
constexpr double cfact(int n) { double r = 1.0; for (int i = 2; i <= n; ++i) r *= i; return r; }
constexpr double csqrt(double x) {
  if (x <= 0.0) return 0.0;
  double r = x > 1.0 ? x : 1.0;
  for (int i = 0; i < 64; ++i) r = 0.5 * (r + x / r);
  return r;
}
constexpr double su2cg(int j1, int m1, int j2, int m2, int j3, int m3) {
  if (m3 != m1 + m2) return 0.0;
  int vmin = -j1 + j2 + m3; if (-j1 + m1 > vmin) vmin = -j1 + m1; if (vmin < 0) vmin = 0;
  int vmax = j2 + j3 + m1; if (j3 - j1 + j2 < vmax) vmax = j3 - j1 + j2; if (j3 + m3 < vmax) vmax = j3 + m3;
  double C = csqrt((2.0 * j3 + 1.0)
                   * cfact(j3 + j1 - j2) * cfact(j3 - j1 + j2) * cfact(j1 + j2 - j3)
                   * cfact(j3 + m3) * cfact(j3 - m3)
                   / (cfact(j1 + j2 + j3 + 1) * cfact(j1 - m1) * cfact(j1 + m1)
                      * cfact(j2 - m2) * cfact(j2 + m2)));
  double S = 0.0;
  for (int v = vmin; v <= vmax; ++v) {
    double sgn = ((v + j2 + m2) & 1) ? -1.0 : 1.0;
    S += sgn * cfact(j2 + j3 + m1 - v) * cfact(j1 - m1 + v)
         / (cfact(v) * cfact(j3 - j1 + j2 - v) * cfact(j3 + m3 - v) * cfact(v + j1 - j2 - m3));
  }
  return C * S;
}

struct Cx { double re, im; };
constexpr Cx cxmul(Cx a, Cx b) { return Cx{a.re * b.re - a.im * b.im, a.re * b.im + a.im * b.re}; }
struct Row { int cnt; int col[2]; Cx v[2]; };

constexpr Row c2r_row(int l, int r) {
  Row out{0, {0, 0}, {{0, 0}, {0, 0}}};
  constexpr double is2 = 0.70710678118654752440;
  const int m = r - l;
  if (m < 0) {
    out.cnt = 2;
    out.col[0] = l - m; out.v[0] = Cx{is2, 0.0};
    out.col[1] = l + m; out.v[1] = Cx{0.0, -is2};
  } else if (m == 0) {
    out.cnt = 1; out.col[0] = l; out.v[0] = Cx{1.0, 0.0};
  } else {
    const double sgn = (m & 1) ? -1.0 : 1.0;
    out.cnt = 2;
    out.col[0] = l + m; out.v[0] = Cx{sgn * is2, 0.0};
    out.col[1] = l - m; out.v[1] = Cx{0.0, sgn * is2};
  }
  const int ph = l & 3;
  for (int a = 0; a < out.cnt; ++a) {
    Cx v = out.v[a];
    out.v[a] = (ph == 0) ? v
             : (ph == 1) ? Cx{v.im, -v.re}
             : (ph == 2) ? Cx{-v.re, -v.im}
                         : Cx{-v.im, v.re};
  }
  return out;
}

struct CGAll { float v[1105]; };
constexpr CGAll make_cg() {
  CGAll R{};
  for (int t = 0; t < 19; ++t) {
    const int l1 = T_L1c[t], l2 = T_L2c[t], l3 = T_L3c[t], off = T_OFFc[t];
    const int d1 = 2 * l1 + 1, d2 = 2 * l2 + 1, d3 = 2 * l3 + 1;
    double tmp[175] = {};
    for (int i = 0; i < d1; ++i) {
      const int m1 = i - l1;
      const Row r1 = c2r_row(l1, i);
      for (int k = 0; k < d2; ++k) {
        const int m2 = k - l2, m3 = m1 + m2;
        if (m3 < -l3 || m3 > l3) continue;
        const double cc = su2cg(l1, m1, l2, m2, l3, m3);
        if (cc == 0.0) continue;
        const Row r2 = c2r_row(l2, k);
        const Row r3 = c2r_row(l3, m3 + l3);
        for (int a = 0; a < r1.cnt; ++a)
          for (int b = 0; b < r2.cnt; ++b) {
            const Cx q12 = cxmul(r1.v[a], r2.v[b]);
            for (int cdx = 0; cdx < r3.cnt; ++cdx) {
              const double re = q12.re * r3.v[cdx].re + q12.im * r3.v[cdx].im;
              tmp[(r1.col[a] * d2 + r2.col[b]) * d3 + r3.col[cdx]] += re * cc;
            }
          }
      }
    }
    const int sz = d1 * d2 * d3;
    for (int e = 0; e < sz; ++e) R.v[off + e] = (float)tmp[e];
  }
  return R;
}
constexpr CGAll CG_ALL = make_cg();

constexpr bool check_cg_sym() {
  for (int t = 0; t < 18; ++t) {
    const int tc = TT_CANONc[t];
    if (tc == t) continue;
    const int l1 = K_L1c[t], l2 = K_L2c[t], l12 = K_L12c[t];
    const int d1 = 2*l1+1, d2 = 2*l2+1, d12 = 2*l12+1;
    for (int i = 0; i < d1; ++i)
      for (int j = 0; j < d2; ++j)
        for (int k = 0; k < d12; ++k) {
          float a = CG_ALL.v[T_OFFc[t]  + (i*d2 + j)*d12 + k];
          float b = TT_SGNc[t] * CG_ALL.v[T_OFFc[tc] + (j*d1 + i)*d12 + k];
          float d = a - b; if (d < 0) d = -d;
          if (d > 1e-5f) return false;
        }
  }
  return true;
}
static_assert(check_cg_sym(), "CG exchange symmetry violated");

// ============================ basis kernel =====================================
// 2 channels per thread via packed fp32 (v_pk_fma_f32). Block=256thr=4 nodes
// (wave = 1 node -> species wave-uniform). Writes B to d_ws [n][c] float4.
__global__ __launch_bounds__(256) void epb_basis(
    const float* __restrict__ nf,      // [N, C, 9]
    const float* __restrict__ w1,      // [E, 2, C]
    const float* __restrict__ w2,      // [E, 9, C]
    const float* __restrict__ w3,      // [E, 51, C]
    const int*   __restrict__ species, // [N]
    float4* __restrict__ Bws)          // [N, C]
{
  const int t  = threadIdx.x;
  const int nb = blockIdx.x * 4;
  const int nl = t >> 6;               // wave-uniform node
  const int c0 = (t & 63) * 2;         // channel pair
  const int n  = nb + nl;
  const int s  = species[n];

  const float* ap = nf + ((size_t)n * NC + c0) * 9;
  v2f A[9];
  sfor<9>([&](auto I) { A[I.value] = v2f{ap[I.value], ap[I.value + 9]}; });

  const float* w1p = w1 + (size_t)s * 2  * NC + c0;
  const float* w2p = w2 + (size_t)s * 9  * NC + c0;
  const float* w3p = w3 + (size_t)s * 51 * NC + c0;

  v2f B[4];
  {
    const v2f wa = ld2(w1p), wb = ld2(w1p + NC);
    B[0] = wa * A[0];
    B[1] = wb * A[1];
    B[2] = wb * A[2];
    B[3] = wb * A[3];
  }

  // ---- order 2 (unique paths, merged weights)
  sfor<7>([&](auto P) {
    constexpr int p  = P.value;
    constexpr int l1 = P2U_L1c[p], l2 = P2U_L2c[p], lo = P2U_LOc[p];
    constexpr int d1 = 2*l1+1, d2 = 2*l2+1, dl = 2*lo+1;
    constexpr int off = T_OFFc[P2U_TBLc[p]];
    v2f w = ld2(w2p + P2U_WAc[p] * NC);
    if constexpr (P2U_WBc[p] >= 0) w = w + ld2(w2p + P2U_WBc[p] * NC);
    sfor<dl>([&](auto Kk) {
      constexpr int k = Kk.value;
      v2f v = {0.f, 0.f};
      sfor<d1>([&](auto I) {
        sfor<d2>([&](auto J) {
          constexpr float cgc = CG_ALL.v[off + (I.value * d2 + J.value) * dl + k];
          if constexpr (cgc != 0.0f) {
            constexpr int ia = AOFFc[l1] + I.value, ja = AOFFc[l2] + J.value;
            constexpr int x = ia < ja ? ia : ja, y = ia < ja ? ja : ia;
            v = cfma(cgc, A[x] * A[y], v);
          }
        });
      });
      B[lo + k] = vfma(w, v, B[lo + k]);
    });
  });

  // ---- order 3: 13 canonical T12 keys; duplicate keys consume shared tt
  sfor<13>([&](auto CI) {
    constexpr int tk  = CANONc[CI.value];
    constexpr int l1  = K_L1c[tk], l2 = K_L2c[tk], l12 = K_L12c[tk];
    constexpr int d1  = 2*l1+1, d2 = 2*l2+1, d12 = 2*l12+1;
    constexpr int off = T_OFFc[tk];
    v2f tt[d12];
    sfor<d12>([&](auto Kk) {
      constexpr int k = Kk.value;
      v2f v = {0.f, 0.f};
      sfor<d1>([&](auto I) {
        sfor<d2>([&](auto J) {
          constexpr float cgc = CG_ALL.v[off + (I.value * d2 + J.value) * d12 + k];
          if constexpr (cgc != 0.0f) {
            constexpr int ia = AOFFc[l1] + I.value, ja = AOFFc[l2] + J.value;
            constexpr int x = ia < ja ? ia : ja, y = ia < ja ? ja : ia;
            v = cfma(cgc, A[x] * A[y], v);
          }
        });
      });
      tt[k] = v;
    });

    auto consume = [&](auto TK, auto SG) {
      constexpr int tkey = TK.value;
      constexpr float sgn = (float)SG.value;
      constexpr int pcnt = P3_STARTc[tkey + 1] - P3_STARTc[tkey];
      sfor<pcnt>([&](auto PP) {
        constexpr int p  = P3_STARTc[tkey] + PP.value;
        constexpr int l3 = P3_L3c[p], lo = P3_LOc[p];
        constexpr int d3 = 2*l3+1, dl = 2*lo+1;
        constexpr int off2 = T_OFFc[P3_TBLc[p]];
        const v2f w = ld2(w3p + p * NC);
        sfor<dl>([&](auto M) {
          v2f v = {0.f, 0.f};
          sfor<d12>([&](auto Kk) {
            sfor<d3>([&](auto J) {
              constexpr float cgc = sgn * CG_ALL.v[off2 + (Kk.value * d3 + J.value) * dl + M.value];
              if constexpr (cgc != 0.0f)
                v = cfma(cgc, tt[Kk.value] * A[AOFFc[l3] + J.value], v);
            });
          });
          B[lo + M.value] = vfma(w, v, B[lo + M.value]);
        });
      });
    };
    consume(std::integral_constant<int, tk>{}, std::integral_constant<int, 1>{});
    constexpr int td = CONS2c[CI.value];
    if constexpr (td >= 0)
      consume(std::integral_constant<int, td>{},
              std::integral_constant<int, (int)TT_SGNc[td]>{});
  });

  Bws[(size_t)n * NC + c0]     = make_float4(B[0].x, B[1].x, B[2].x, B[3].x);
  Bws[(size_t)n * NC + c0 + 1] = make_float4(B[0].y, B[1].y, B[2].y, B[3].y);
}

// ============================ linear kernel ====================================
// Small looped code. Block=256thr, 8 nodes. Thread = (f-quad, node).
__global__ __launch_bounds__(256) void epb_linear(
    const float4* __restrict__ Bws,    // [N, C]
    const float*  __restrict__ lw0,    // [C, F]
    const float*  __restrict__ lw1,    // [C, F]
    float* __restrict__ out)           // [N, F, 4]
{
  __shared__ float4 Bsh[8 * NC];       // 16 KB
  const int t  = threadIdx.x;
  const int nb = blockIdx.x * 8;

  const float4* src = Bws + (size_t)nb * NC;
  #pragma unroll
  for (int i = 0; i < 4; ++i) Bsh[t + 256 * i] = src[t + 256 * i];
  __syncthreads();

  const int q = t & 31;                // features 4q..4q+3
  const int g = t >> 5;                // node 0..7
  const float4* pa = reinterpret_cast<const float4*>(lw0) + q;
  const float4* pb = reinterpret_cast<const float4*>(lw1) + q;
  const float4* bp = &Bsh[g * NC];

  float4 o0{0,0,0,0}, o1{0,0,0,0}, o2{0,0,0,0}, o3{0,0,0,0};

  #pragma unroll 4
  for (int ch = 0; ch < NC; ++ch) {
    const float4 wa = pa[ch * 32];     // dwordx4, coalesced, L1-reused across g
    const float4 wb = pb[ch * 32];
    const float4 b  = bp[ch];          // wave-uniform -> LDS broadcast
    o0.x = fmaf(b.x, wa.x, o0.x); o0.y = fmaf(b.y, wb.x, o0.y);
    o0.z = fmaf(b.z, wb.x, o0.z); o0.w = fmaf(b.w, wb.x, o0.w);
    o1.x = fmaf(b.x, wa.y, o1.x); o1.y = fmaf(b.y, wb.y, o1.y);
    o1.z = fmaf(b.z, wb.y, o1.z); o1.w = fmaf(b.w, wb.y, o1.w);
    o2.x = fmaf(b.x, wa.z, o2.x); o2.y = fmaf(b.y, wb.z, o2.y);
    o2.z = fmaf(b.z, wb.z, o2.z); o2.w = fmaf(b.w, wb.z, o2.w);
    o3.x = fmaf(b.x, wa.w, o3.x); o3.y = fmaf(b.y, wb.w, o3.y);
    o3.z = fmaf(b.z, wb.w, o3.z); o3.w = fmaf(b.w, wb.w, o3.w);
  }

  const float s4 = 0.08838834764831845f;  // 1/sqrt(128)
  float4* out4 = reinterpret_cast<float4*>(out) + (size_t)(nb + g) * NC + 4 * q;
  out4[0] = make_float4(o0.x*s4, o0.y*s4, o0.z*s4, o0.w*s4);
  out4[1] = make_float4(o1.x*s4, o1.y*s4, o1.z*s4, o1.w*s4);
  out4[2] = make_float4(o2.x*s4, o2.y*s4, o2.z*s4, o2.w*s4);
  out4[3] = make_float4(o3.x*s4, o3.y*s4, o3.z*s4, o3.w*s4);
}

// ------------------------------- launcher --------------------------------------
extern "C" void kernel_launch(void* const* d_in, const int* in_sizes, int n_in,
                              void* d_out, int out_size, void* d_ws, size_t ws_size,
                              hipStream_t stream) {
  const float* nf  = (const float*)d_in[0];
  const float* w1  = (const float*)d_in[1];
  const float* w2  = (const float*)d_in[2];
  const float* w3  = (const float*)d_in[3];
  const float* lw0 = (const float*)d_in[4];
  const float* lw1 = (const float*)d_in[5];
  const int*   spc = (const int*)  d_in[6];
  float* out = (float*)d_out;
  float4* Bws = (float4*)d_ws;   // [N][C] float4 = 8 MB, rebuilt each launch
  (void)ws_size; (void)in_sizes; (void)n_in; (void)out_size;

  hipLaunchKernelGGL(epb_basis, dim3(NN / 4), dim3(256), 0, stream,
                     nf, w1, w2, w3, spc, Bws);
  hipLaunchKernelGGL(epb_linear, dim3(NN / 8), dim3(256), 0, stream,
                     Bws, lw0, lw1, out);
}

// Round 10
// 106.309 us; speedup vs baseline: 1.1957x; 1.1957x over previous
//
#include <hip/hip_runtime.h>
#include <utility>

// EquivariantProductBasisBlock (MACE-style) for gfx950 — round 10.
// R9 split localized the bottleneck: epb_basis ~18us (packed fp32 worked),
// epb_linear 48-58us @ VGPR=28 -> single load-group in flight, pure latency
// serialization + 512-block grid. R10: linear rewritten — TN=4 (1024 blocks),
// thread = (quad, node, ch-half), 8-ch chunks with named prefetch arrays
// (constexpr-indexed -> SROA keeps them in VGPRs), 16 independent accumulators,
// LDS reduction over ch-halves. Basis kernel unchanged.

#define NN 4096
#define NC 128
#define NE 10

typedef float v2f __attribute__((ext_vector_type(2)));

__device__ __forceinline__ v2f ld2(const float* p) {
  return *reinterpret_cast<const v2f*>(p);
}
__device__ __forceinline__ v2f cfma(float c, v2f x, v2f a) {  // a += c*x (splat c)
  v2f cc = {c, c};
  return __builtin_elementwise_fma(cc, x, a);
}
__device__ __forceinline__ v2f vfma(v2f w, v2f x, v2f a) {    // a += w*x
  return __builtin_elementwise_fma(w, x, a);
}

// ---------------------------- static_for ---------------------------------------
template<typename F, int... Is>
__device__ __forceinline__ void sfor_impl(F&& f, std::integer_sequence<int, Is...>) {
  (f(std::integral_constant<int, Is>{}), ...);
}
template<int N, typename F>
__device__ __forceinline__ void sfor(F&& f) {
  sfor_impl((F&&)f, std::make_integer_sequence<int, N>{});
}

// ---------------------------- CG metadata (constexpr) --------------------------
constexpr int T_L1c[19]  = {0,0,0,1,1,1,1,1,1,1,2,2,2,2,2,2,2,2,3};
constexpr int T_L2c[19]  = {0,1,2,0,1,1,1,2,2,2,0,1,1,1,2,2,2,2,2};
constexpr int T_L3c[19]  = {0,1,2,1,0,1,2,1,2,3,2,1,2,3,0,1,2,3,1};
constexpr int T_OFFc[19] = {0,1,10,35,44,53,80,125,170,245,350,375,420,495,600,625,700,825,1000};
constexpr int AOFFc[3]   = {0,1,4};

constexpr int P2U_L1c[7]  = {0,0,1,1,1,2,2};
constexpr int P2U_L2c[7]  = {0,1,1,1,2,2,2};
constexpr int P2U_LOc[7]  = {0,1,0,1,1,0,1};
constexpr int P2U_TBLc[7] = {0,1,4,5,7,14,15};
constexpr int P2U_WAc[7]  = {0,1,3,4,5,7,8};
constexpr int P2U_WBc[7]  = {-1,2,-1,-1,6,-1,-1};

constexpr int K_L1c[18]  = {0,0,0,1,1,1,1,1,1,1,2,2,2,2,2,2,2,2};
constexpr int K_L2c[18]  = {0,1,2,0,1,1,1,2,2,2,0,1,1,1,2,2,2,2};
constexpr int K_L12c[18] = {0,1,2,1,0,1,2,1,2,3,2,1,2,3,0,1,2,3};

constexpr int   TT_CANONc[18] = {0,1,2,1,4,5,6,7,8,9,2,7,8,9,14,15,16,17};
constexpr float TT_SGNc[18]   = {1,1,1,1,1,1,1,1,1,1,1,1,-1,1,1,1,1,1};
constexpr int CANONc[13] = {0,1,2,4,5,6,7,8,9,14,15,16,17};
constexpr int CONS2c[13] = {-1,3,10,-1,-1,-1,11,12,13,-1,-1,-1,-1};

constexpr int P3_STARTc[19] = {0,2,6,9,13,15,19,22,26,29,30,33,37,40,41,43,47,50,51};
constexpr int P3_L3c[51] = {
  0,1,  0,1,1,2,  1,2,2,  0,1,1,2,  0,1,  0,1,1,2,  1,2,2,  0,1,1,2,  1,2,2,
  2,  1,2,2,  0,1,1,2,  1,2,2,  2,  0,1,  0,1,1,2,  1,2,2,  2 };
constexpr int P3_LOc[51] = {
  0,1,  1,0,1,1,  1,0,1,  1,0,1,1,  0,1,  1,0,1,1,  1,0,1,  1,0,1,1,  1,0,1,
  1,  1,0,1,  1,0,1,1,  1,0,1,  1,  0,1,  1,0,1,1,  1,0,1,  1 };
constexpr int P3_TBLc[51] = {
  0,1,  3,4,5,7,  11,14,15,  3,4,5,7,  0,1,  3,4,5,7,  11,14,15,  3,4,5,7,
  11,14,15,  18,  11,14,15,  3,4,5,7,  11,14,15,  18,  0,1,  3,4,5,7,
  11,14,15,  18 };

// ---------------------------- constexpr CG computation -------------------------
constexpr double cfact(int n) { double r = 1.0; for (int i = 2; i <= n; ++i) r *= i; return r; }
constexpr double csqrt(double x) {
  if (x <= 0.0) return 0.0;
  double r = x > 1.0 ? x : 1.0;
  for (int i = 0; i < 64; ++i) r = 0.5 * (r + x / r);
  return r;
}
constexpr double su2cg(int j1, int m1, int j2, int m2, int j3, int m3) {
  if (m3 != m1 + m2) return 0.0;
  int vmin = -j1 + j2 + m3; if (-j1 + m1 > vmin) vmin = -j1 + m1; if (vmin < 0) vmin = 0;
  int vmax = j2 + j3 + m1; if (j3 - j1 + j2 < vmax) vmax = j3 - j1 + j2; if (j3 + m3 < vmax) vmax = j3 + m3;
  double C = csqrt((2.0 * j3 + 1.0)
                   * cfact(j3 + j1 - j2) * cfact(j3 - j1 + j2) * cfact(j1 + j2 - j3)
                   * cfact(j3 + m3) * cfact(j3 - m3)
                   / (cfact(j1 + j2 + j3 + 1) * cfact(j1 - m1) * cfact(j1 + m1)
                      * cfact(j2 - m2) * cfact(j2 + m2)));
  double S = 0.0;
  for (int v = vmin; v <= vmax; ++v) {
    double sgn = ((v + j2 + m2) & 1) ? -1.0 : 1.0;
    S += sgn * cfact(j2 + j3 + m1 - v) * cfact(j1 - m1 + v)
         / (cfact(v) * cfact(j3 - j1 + j2 - v) * cfact(j3 + m3 - v) * cfact(v + j1 - j2 - m3));
  }
  return C * S;
}

struct Cx { double re, im; };
constexpr Cx cxmul(Cx a, Cx b) { return Cx{a.re * b.re - a.im * b.im, a.re * b.im + a.im * b.re}; }
struct Row { int cnt; int col[2]; Cx v[2]; };

constexpr Row c2r_row(int l, int r) {
  Row out{0, {0, 0}, {{0, 0}, {0, 0}}};
  constexpr double is2 = 0.70710678118654752440;
  const int m = r - l;
  if (m < 0) {
    out.cnt = 2;
    out.col[0] = l - m; out.v[0] = Cx{is2, 0.0};
    out.col[1] = l + m; out.v[1] = Cx{0.0, -is2};
  } else if (m == 0) {
    out.cnt = 1; out.col[0] = l; out.v[0] = Cx{1.0, 0.0};
  } else {
    const double sgn = (m & 1) ? -1.0 : 1.0;
    out.cnt = 2;
    out.col[0] = l + m; out.v[0] = Cx{sgn * is2, 0.0};
    out.col[1] = l - m; out.v[1] = Cx{0.0, sgn * is2};
  }
  const int ph = l & 3;
  for (int a = 0; a < out.cnt; ++a) {
    Cx v = out.v[a];
    out.v[a] = (ph == 0) ? v
             : (ph == 1) ? Cx{v.im, -v.re}
             : (ph == 2) ? Cx{-v.re, -v.im}
                         : Cx{-v.im, v.re};
  }
  return out;
}

struct CGAll { float v[1105]; };
constexpr CGAll make_cg() {
  CGAll R{};
  for (int t = 0; t < 19; ++t) {
    const int l1 = T_L1c[t], l2 = T_L2c[t], l3 = T_L3c[t], off = T_OFFc[t];
    const int d1 = 2 * l1 + 1, d2 = 2 * l2 + 1, d3 = 2 * l3 + 1;
    double tmp[175] = {};
    for (int i = 0; i < d1; ++i) {
      const int m1 = i - l1;
      const Row r1 = c2r_row(l1, i);
      for (int k = 0; k < d2; ++k) {
        const int m2 = k - l2, m3 = m1 + m2;
        if (m3 < -l3 || m3 > l3) continue;
        const double cc = su2cg(l1, m1, l2, m2, l3, m3);
        if (cc == 0.0) continue;
        const Row r2 = c2r_row(l2, k);
        const Row r3 = c2r_row(l3, m3 + l3);
        for (int a = 0; a < r1.cnt; ++a)
          for (int b = 0; b < r2.cnt; ++b) {
            const Cx q12 = cxmul(r1.v[a], r2.v[b]);
            for (int cdx = 0; cdx < r3.cnt; ++cdx) {
              const double re = q12.re * r3.v[cdx].re + q12.im * r3.v[cdx].im;
              tmp[(r1.col[a] * d2 + r2.col[b]) * d3 + r3.col[cdx]] += re * cc;
            }
          }
      }
    }
    const int sz = d1 * d2 * d3;
    for (int e = 0; e < sz; ++e) R.v[off + e] = (float)tmp[e];
  }
  return R;
}
constexpr CGAll CG_ALL = make_cg();

constexpr bool check_cg_sym() {
  for (int t = 0; t < 18; ++t) {
    const int tc = TT_CANONc[t];
    if (tc == t) continue;
    const int l1 = K_L1c[t], l2 = K_L2c[t], l12 = K_L12c[t];
    const int d1 = 2*l1+1, d2 = 2*l2+1, d12 = 2*l12+1;
    for (int i = 0; i < d1; ++i)
      for (int j = 0; j < d2; ++j)
        for (int k = 0; k < d12; ++k) {
          float a = CG_ALL.v[T_OFFc[t]  + (i*d2 + j)*d12 + k];
          float b = TT_SGNc[t] * CG_ALL.v[T_OFFc[tc] + (j*d1 + i)*d12 + k];
          float d = a - b; if (d < 0) d = -d;
          if (d > 1e-5f) return false;
        }
  }
  return true;
}
static_assert(check_cg_sym(), "CG exchange symmetry violated");

// ============================ basis kernel (unchanged from R9) =================
__global__ __launch_bounds__(256) void epb_basis(
    const float* __restrict__ nf,      // [N, C, 9]
    const float* __restrict__ w1,      // [E, 2, C]
    const float* __restrict__ w2,      // [E, 9, C]
    const float* __restrict__ w3,      // [E, 51, C]
    const int*   __restrict__ species, // [N]
    float4* __restrict__ Bws)          // [N, C]
{
  const int t  = threadIdx.x;
  const int nb = blockIdx.x * 4;
  const int nl = t >> 6;               // wave-uniform node
  const int c0 = (t & 63) * 2;         // channel pair
  const int n  = nb + nl;
  const int s  = species[n];

  const float* ap = nf + ((size_t)n * NC + c0) * 9;
  v2f A[9];
  sfor<9>([&](auto I) { A[I.value] = v2f{ap[I.value], ap[I.value + 9]}; });

  const float* w1p = w1 + (size_t)s * 2  * NC + c0;
  const float* w2p = w2 + (size_t)s * 9  * NC + c0;
  const float* w3p = w3 + (size_t)s * 51 * NC + c0;

  v2f B[4];
  {
    const v2f wa = ld2(w1p), wb = ld2(w1p + NC);
    B[0] = wa * A[0];
    B[1] = wb * A[1];
    B[2] = wb * A[2];
    B[3] = wb * A[3];
  }

  sfor<7>([&](auto P) {
    constexpr int p  = P.value;
    constexpr int l1 = P2U_L1c[p], l2 = P2U_L2c[p], lo = P2U_LOc[p];
    constexpr int d1 = 2*l1+1, d2 = 2*l2+1, dl = 2*lo+1;
    constexpr int off = T_OFFc[P2U_TBLc[p]];
    v2f w = ld2(w2p + P2U_WAc[p] * NC);
    if constexpr (P2U_WBc[p] >= 0) w = w + ld2(w2p + P2U_WBc[p] * NC);
    sfor<dl>([&](auto Kk) {
      constexpr int k = Kk.value;
      v2f v = {0.f, 0.f};
      sfor<d1>([&](auto I) {
        sfor<d2>([&](auto J) {
          constexpr float cgc = CG_ALL.v[off + (I.value * d2 + J.value) * dl + k];
          if constexpr (cgc != 0.0f) {
            constexpr int ia = AOFFc[l1] + I.value, ja = AOFFc[l2] + J.value;
            constexpr int x = ia < ja ? ia : ja, y = ia < ja ? ja : ia;
            v = cfma(cgc, A[x] * A[y], v);
          }
        });
      });
      B[lo + k] = vfma(w, v, B[lo + k]);
    });
  });

  sfor<13>([&](auto CI) {
    constexpr int tk  = CANONc[CI.value];
    constexpr int l1  = K_L1c[tk], l2 = K_L2c[tk], l12 = K_L12c[tk];
    constexpr int d1  = 2*l1+1, d2 = 2*l2+1, d12 = 2*l12+1;
    constexpr int off = T_OFFc[tk];
    v2f tt[d12];
    sfor<d12>([&](auto Kk) {
      constexpr int k = Kk.value;
      v2f v = {0.f, 0.f};
      sfor<d1>([&](auto I) {
        sfor<d2>([&](auto J) {
          constexpr float cgc = CG_ALL.v[off + (I.value * d2 + J.value) * d12 + k];
          if constexpr (cgc != 0.0f) {
            constexpr int ia = AOFFc[l1] + I.value, ja = AOFFc[l2] + J.value;
            constexpr int x = ia < ja ? ia : ja, y = ia < ja ? ja : ia;
            v = cfma(cgc, A[x] * A[y], v);
          }
        });
      });
      tt[k] = v;
    });

    auto consume = [&](auto TK, auto SG) {
      constexpr int tkey = TK.value;
      constexpr float sgn = (float)SG.value;
      constexpr int pcnt = P3_STARTc[tkey + 1] - P3_STARTc[tkey];
      sfor<pcnt>([&](auto PP) {
        constexpr int p  = P3_STARTc[tkey] + PP.value;
        constexpr int l3 = P3_L3c[p], lo = P3_LOc[p];
        constexpr int d3 = 2*l3+1, dl = 2*lo+1;
        constexpr int off2 = T_OFFc[P3_TBLc[p]];
        const v2f w = ld2(w3p + p * NC);
        sfor<dl>([&](auto M) {
          v2f v = {0.f, 0.f};
          sfor<d12>([&](auto Kk) {
            sfor<d3>([&](auto J) {
              constexpr float cgc = sgn * CG_ALL.v[off2 + (Kk.value * d3 + J.value) * dl + M.value];
              if constexpr (cgc != 0.0f)
                v = cfma(cgc, tt[Kk.value] * A[AOFFc[l3] + J.value], v);
            });
          });
          B[lo + M.value] = vfma(w, v, B[lo + M.value]);
        });
      });
    };
    consume(std::integral_constant<int, tk>{}, std::integral_constant<int, 1>{});
    constexpr int td = CONS2c[CI.value];
    if constexpr (td >= 0)
      consume(std::integral_constant<int, td>{},
              std::integral_constant<int, (int)TT_SGNc[td]>{});
  });

  Bws[(size_t)n * NC + c0]     = make_float4(B[0].x, B[1].x, B[2].x, B[3].x);
  Bws[(size_t)n * NC + c0 + 1] = make_float4(B[0].y, B[1].y, B[2].y, B[3].y);
}

// ============================ linear kernel (rewritten) ========================
// TN=4 nodes/block (1024 blocks). Thread = (quad q, node nl, ch-half h).
// 8-channel chunks with named prefetch arrays -> 16 dwordx4 in flight.
__global__ __launch_bounds__(256) void epb_linear(
    const float4* __restrict__ Bws,    // [N, C]
    const float*  __restrict__ lw0,    // [C, F]
    const float*  __restrict__ lw1,    // [C, F]
    float* __restrict__ out)           // [N, F, 4]
{
  __shared__ float4 Bsh[4 * NC];       // 8 KB
  __shared__ float4 psh[2 * 4 * NC];   // 16 KB  [h][node][feature]
  const int t  = threadIdx.x;
  const int nb = blockIdx.x * 4;

  {
    const float4* src = Bws + (size_t)nb * NC;
    Bsh[t]       = src[t];
    Bsh[t + 256] = src[t + 256];
  }
  __syncthreads();

  const int q  = t & 31;               // features 4q..4q+3
  const int nl = (t >> 5) & 3;         // node
  const int h  = t >> 7;               // ch-half: channels h*64..h*64+63
  const float4* pa = reinterpret_cast<const float4*>(lw0) + (size_t)h * 64 * 32 + q;
  const float4* pb = reinterpret_cast<const float4*>(lw1) + (size_t)h * 64 * 32 + q;
  const float4* bp = &Bsh[nl * NC + h * 64];

  float4 o0{0,0,0,0}, o1{0,0,0,0}, o2{0,0,0,0}, o3{0,0,0,0};

  for (int cb = 0; cb < 64; cb += 8) {
    float4 wa[8], wb[8], bb[8];
    sfor<8>([&](auto I) { wa[I.value] = pa[(cb + I.value) * 32]; });
    sfor<8>([&](auto I) { wb[I.value] = pb[(cb + I.value) * 32]; });
    sfor<8>([&](auto I) { bb[I.value] = bp[cb + I.value]; });
    sfor<8>([&](auto I) {
      const float4 a = wa[I.value], w = wb[I.value], b = bb[I.value];
      o0.x = fmaf(b.x, a.x, o0.x); o0.y = fmaf(b.y, w.x, o0.y);
      o0.z = fmaf(b.z, w.x, o0.z); o0.w = fmaf(b.w, w.x, o0.w);
      o1.x = fmaf(b.x, a.y, o1.x); o1.y = fmaf(b.y, w.y, o1.y);
      o1.z = fmaf(b.z, w.y, o1.z); o1.w = fmaf(b.w, w.y, o1.w);
      o2.x = fmaf(b.x, a.z, o2.x); o2.y = fmaf(b.y, w.z, o2.y);
      o2.z = fmaf(b.z, w.z, o2.z); o2.w = fmaf(b.w, w.z, o2.w);
      o3.x = fmaf(b.x, a.w, o3.x); o3.y = fmaf(b.y, w.w, o3.y);
      o3.z = fmaf(b.z, w.w, o3.z); o3.w = fmaf(b.w, w.w, o3.w);
    });
  }

  {
    float4* pp = &psh[((h * 4 + nl) * NC) + 4 * q];
    pp[0] = o0; pp[1] = o1; pp[2] = o2; pp[3] = o3;
  }
  __syncthreads();

  // reduce the two ch-halves; 512 outputs over 256 threads (2 each)
  const float s4 = 0.08838834764831845f;  // 1/sqrt(128)
  #pragma unroll
  for (int i = 0; i < 2; ++i) {
    const int item = t + 256 * i;
    const int n2 = item >> 7, f = item & 127;
    const float4 pA = psh[((0 * 4 + n2) * NC) + f];
    const float4 pB = psh[((1 * 4 + n2) * NC) + f];
    float4 r;
    r.x = (pA.x + pB.x) * s4;
    r.y = (pA.y + pB.y) * s4;
    r.z = (pA.z + pB.z) * s4;
    r.w = (pA.w + pB.w) * s4;
    reinterpret_cast<float4*>(out)[(size_t)(nb + n2) * NC + f] = r;
  }
}

// ------------------------------- launcher --------------------------------------
extern "C" void kernel_launch(void* const* d_in, const int* in_sizes, int n_in,
                              void* d_out, int out_size, void* d_ws, size_t ws_size,
                              hipStream_t stream) {
  const float* nf  = (const float*)d_in[0];
  const float* w1  = (const float*)d_in[1];
  const float* w2  = (const float*)d_in[2];
  const float* w3  = (const float*)d_in[3];
  const float* lw0 = (const float*)d_in[4];
  const float* lw1 = (const float*)d_in[5];
  const int*   spc = (const int*)  d_in[6];
  float* out = (float*)d_out;
  float4* Bws = (float4*)d_ws;   // [N][C] float4 = 8 MB, rebuilt each launch
  (void)ws_size; (void)in_sizes; (void)n_in; (void)out_size;

  hipLaunchKernelGGL(epb_basis, dim3(NN / 4), dim3(256), 0, stream,
                     nf, w1, w2, w3, spc, Bws);
  hipLaunchKernelGGL(epb_linear, dim3(NN / 4), dim3(256), 0, stream,
                     Bws, lw0, lw1, out);
}

// Round 11
// 103.258 us; speedup vs baseline: 1.2310x; 1.0295x over previous
//
#include <hip/hip_runtime.h>
#include <utility>

// EquivariantProductBasisBlock (MACE-style) for gfx950 — round 11.
// R10 accounting: timed region = 44us d_ws fill + ~18us fixed + kernels.
// Kernels: basis ~18us, linear ~26us. Linear was streaming 64KB of weights
// per wave from L2 (268MB total) -> latency/BW bound. R11: linear stages
// weights in LDS once per block (2 phases x 32KB) amortized over TN=8 nodes;
// per-ch iter = 3 conflict-free ds_read_b128 + 16 FMA -> VALU-bound.
// Weight L2 traffic 268MB -> 64MB. Basis kernel unchanged (R9).
// Learned R10: v_pk_fma_f32 is NOT 2x FLOP rate on gfx950 (fp32 peak = scalar
// fma rate); v2f packing helps instruction count / I-fetch only.

#define NN 4096
#define NC 128
#define NE 10
#define LTN 8   // nodes per linear block

typedef float v2f __attribute__((ext_vector_type(2)));

__device__ __forceinline__ v2f ld2(const float* p) {
  return *reinterpret_cast<const v2f*>(p);
}
__device__ __forceinline__ v2f cfma(float c, v2f x, v2f a) {  // a += c*x (splat c)
  v2f cc = {c, c};
  return __builtin_elementwise_fma(cc, x, a);
}
__device__ __forceinline__ v2f vfma(v2f w, v2f x, v2f a) {    // a += w*x
  return __builtin_elementwise_fma(w, x, a);
}

// ---------------------------- static_for ---------------------------------------
template<typename F, int... Is>
__device__ __forceinline__ void sfor_impl(F&& f, std::integer_sequence<int, Is...>) {
  (f(std::integral_constant<int, Is>{}), ...);
}
template<int N, typename F>
__device__ __forceinline__ void sfor(F&& f) {
  sfor_impl((F&&)f, std::make_integer_sequence<int, N>{});
}

// ---------------------------- CG metadata (constexpr) --------------------------
constexpr int T_L1c[19]  = {0,0,0,1,1,1,1,1,1,1,2,2,2,2,2,2,2,2,3};
constexpr int T_L2c[19]  = {0,1,2,0,1,1,1,2,2,2,0,1,1,1,2,2,2,2,2};
constexpr int T_L3c[19]  = {0,1,2,1,0,1,2,1,2,3,2,1,2,3,0,1,2,3,1};
constexpr int T_OFFc[19] = {0,1,10,35,44,53,80,125,170,245,350,375,420,495,600,625,700,825,1000};
constexpr int AOFFc[3]   = {0,1,4};

constexpr int P2U_L1c[7]  = {0,0,1,1,1,2,2};
constexpr int P2U_L2c[7]  = {0,1,1,1,2,2,2};
constexpr int P2U_LOc[7]  = {0,1,0,1,1,0,1};
constexpr int P2U_TBLc[7] = {0,1,4,5,7,14,15};
constexpr int P2U_WAc[7]  = {0,1,3,4,5,7,8};
constexpr int P2U_WBc[7]  = {-1,2,-1,-1,6,-1,-1};

constexpr int K_L1c[18]  = {0,0,0,1,1,1,1,1,1,1,2,2,2,2,2,2,2,2};
constexpr int K_L2c[18]  = {0,1,2,0,1,1,1,2,2,2,0,1,1,1,2,2,2,2};
constexpr int K_L12c[18] = {0,1,2,1,0,1,2,1,2,3,2,1,2,3,0,1,2,3};

constexpr int   TT_CANONc[18] = {0,1,2,1,4,5,6,7,8,9,2,7,8,9,14,15,16,17};
constexpr float TT_SGNc[18]   = {1,1,1,1,1,1,1,1,1,1,1,1,-1,1,1,1,1,1};
constexpr int CANONc[13] = {0,1,2,4,5,6,7,8,9,14,15,16,17};
constexpr int CONS2c[13] = {-1,3,10,-1,-1,-1,11,12,13,-1,-1,-1,-1};

constexpr int P3_STARTc[19] = {0,2,6,9,13,15,19,22,26,29,30,33,37,40,41,43,47,50,51};
constexpr int P3_L3c[51] = {
  0,1,  0,1,1,2,  1,2,2,  0,1,1,2,  0,1,  0,1,1,2,  1,2,2,  0,1,1,2,  1,2,2,
  2,  1,2,2,  0,1,1,2,  1,2,2,  2,  0,1,  0,1,1,2,  1,2,2,  2 };
constexpr int P3_LOc[51] = {
  0,1,  1,0,1,1,  1,0,1,  1,0,1,1,  0,1,  1,0,1,1,  1,0,1,  1,0,1,1,  1,0,1,
  1,  1,0,1,  1,0,1,1,  1,0,1,  1,  0,1,  1,0,1,1,  1,0,1,  1 };
constexpr int P3_TBLc[51] = {
  0,1,  3,4,5,7,  11,14,15,  3,4,5,7,  0,1,  3,4,5,7,  11,14,15,  3,4,5,7,
  11,14,15,  18,  11,14,15,  3,4,5,7,  11,14,15,  18,  0,1,  3,4,5,7,
  11,14,15,  18 };

// ---------------------------- constexpr CG computation -------------------------
constexpr double cfact(int n) { double r = 1.0; for (int i = 2; i <= n; ++i) r *= i; return r; }
constexpr double csqrt(double x) {
  if (x <= 0.0) return 0.0;
  double r = x > 1.0 ? x : 1.0;
  for (int i = 0; i < 64; ++i) r = 0.5 * (r + x / r);
  return r;
}
constexpr double su2cg(int j1, int m1, int j2, int m2, int j3, int m3) {
  if (m3 != m1 + m2) return 0.0;
  int vmin = -j1 + j2 + m3; if (-j1 + m1 > vmin) vmin = -j1 + m1; if (vmin < 0) vmin = 0;
  int vmax = j2 + j3 + m1; if (j3 - j1 + j2 < vmax) vmax = j3 - j1 + j2; if (j3 + m3 < vmax) vmax = j3 + m3;
  double C = csqrt((2.0 * j3 + 1.0)
                   * cfact(j3 + j1 - j2) * cfact(j3 - j1 + j2) * cfact(j1 + j2 - j3)
                   * cfact(j3 + m3) * cfact(j3 - m3)
                   / (cfact(j1 + j2 + j3 + 1) * cfact(j1 - m1) * cfact(j1 + m1)
                      * cfact(j2 - m2) * cfact(j2 + m2)));
  double S = 0.0;
  for (int v = vmin; v <= vmax; ++v) {
    double sgn = ((v + j2 + m2) & 1) ? -1.0 : 1.0;
    S += sgn * cfact(j2 + j3 + m1 - v) * cfact(j1 - m1 + v)
         / (cfact(v) * cfact(j3 - j1 + j2 - v) * cfact(j3 + m3 - v) * cfact(v + j1 - j2 - m3));
  }
  return C * S;
}

struct Cx { double re, im; };
constexpr Cx cxmul(Cx a, Cx b) { return Cx{a.re * b.re - a.im * b.im, a.re * b.im + a.im * b.re}; }
struct Row { int cnt; int col[2]; Cx v[2]; };

constexpr Row c2r_row(int l, int r) {
  Row out{0, {0, 0}, {{0, 0}, {0, 0}}};
  constexpr double is2 = 0.70710678118654752440;
  const int m = r - l;
  if (m < 0) {
    out.cnt = 2;
    out.col[0] = l - m; out.v[0] = Cx{is2, 0.0};
    out.col[1] = l + m; out.v[1] = Cx{0.0, -is2};
  } else if (m == 0) {
    out.cnt = 1; out.col[0] = l; out.v[0] = Cx{1.0, 0.0};
  } else {
    const double sgn = (m & 1) ? -1.0 : 1.0;
    out.cnt = 2;
    out.col[0] = l + m; out.v[0] = Cx{sgn * is2, 0.0};
    out.col[1] = l - m; out.v[1] = Cx{0.0, sgn * is2};
  }
  const int ph = l & 3;
  for (int a = 0; a < out.cnt; ++a) {
    Cx v = out.v[a];
    out.v[a] = (ph == 0) ? v
             : (ph == 1) ? Cx{v.im, -v.re}
             : (ph == 2) ? Cx{-v.re, -v.im}
                         : Cx{-v.im, v.re};
  }
  return out;
}

struct CGAll { float v[1105]; };
constexpr CGAll make_cg() {
  CGAll R{};
  for (int t = 0; t < 19; ++t) {
    const int l1 = T_L1c[t], l2 = T_L2c[t], l3 = T_L3c[t], off = T_OFFc[t];
    const int d1 = 2 * l1 + 1, d2 = 2 * l2 + 1, d3 = 2 * l3 + 1;
    double tmp[175] = {};
    for (int i = 0; i < d1; ++i) {
      const int m1 = i - l1;
      const Row r1 = c2r_row(l1, i);
      for (int k = 0; k < d2; ++k) {
        const int m2 = k - l2, m3 = m1 + m2;
        if (m3 < -l3 || m3 > l3) continue;
        const double cc = su2cg(l1, m1, l2, m2, l3, m3);
        if (cc == 0.0) continue;
        const Row r2 = c2r_row(l2, k);
        const Row r3 = c2r_row(l3, m3 + l3);
        for (int a = 0; a < r1.cnt; ++a)
          for (int b = 0; b < r2.cnt; ++b) {
            const Cx q12 = cxmul(r1.v[a], r2.v[b]);
            for (int cdx = 0; cdx < r3.cnt; ++cdx) {
              const double re = q12.re * r3.v[cdx].re + q12.im * r3.v[cdx].im;
              tmp[(r1.col[a] * d2 + r2.col[b]) * d3 + r3.col[cdx]] += re * cc;
            }
          }
      }
    }
    const int sz = d1 * d2 * d3;
    for (int e = 0; e < sz; ++e) R.v[off + e] = (float)tmp[e];
  }
  return R;
}
constexpr CGAll CG_ALL = make_cg();

constexpr bool check_cg_sym() {
  for (int t = 0; t < 18; ++t) {
    const int tc = TT_CANONc[t];
    if (tc == t) continue;
    const int l1 = K_L1c[t], l2 = K_L2c[t], l12 = K_L12c[t];
    const int d1 = 2*l1+1, d2 = 2*l2+1, d12 = 2*l12+1;
    for (int i = 0; i < d1; ++i)
      for (int j = 0; j < d2; ++j)
        for (int k = 0; k < d12; ++k) {
          float a = CG_ALL.v[T_OFFc[t]  + (i*d2 + j)*d12 + k];
          float b = TT_SGNc[t] * CG_ALL.v[T_OFFc[tc] + (j*d1 + i)*d12 + k];
          float d = a - b; if (d < 0) d = -d;
          if (d > 1e-5f) return false;
        }
  }
  return true;
}
static_assert(check_cg_sym(), "CG exchange symmetry violated");

// ============================ basis kernel (unchanged from R9) =================
__global__ __launch_bounds__(256) void epb_basis(
    const float* __restrict__ nf,      // [N, C, 9]
    const float* __restrict__ w1,      // [E, 2, C]
    const float* __restrict__ w2,      // [E, 9, C]
    const float* __restrict__ w3,      // [E, 51, C]
    const int*   __restrict__ species, // [N]
    float4* __restrict__ Bws)          // [N, C]
{
  const int t  = threadIdx.x;
  const int nb = blockIdx.x * 4;
  const int nl = t >> 6;               // wave-uniform node
  const int c0 = (t & 63) * 2;         // channel pair
  const int n  = nb + nl;
  const int s  = species[n];

  const float* ap = nf + ((size_t)n * NC + c0) * 9;
  v2f A[9];
  sfor<9>([&](auto I) { A[I.value] = v2f{ap[I.value], ap[I.value + 9]}; });

  const float* w1p = w1 + (size_t)s * 2  * NC + c0;
  const float* w2p = w2 + (size_t)s * 9  * NC + c0;
  const float* w3p = w3 + (size_t)s * 51 * NC + c0;

  v2f B[4];
  {
    const v2f wa = ld2(w1p), wb = ld2(w1p + NC);
    B[0] = wa * A[0];
    B[1] = wb * A[1];
    B[2] = wb * A[2];
    B[3] = wb * A[3];
  }

  sfor<7>([&](auto P) {
    constexpr int p  = P.value;
    constexpr int l1 = P2U_L1c[p], l2 = P2U_L2c[p], lo = P2U_LOc[p];
    constexpr int d1 = 2*l1+1, d2 = 2*l2+1, dl = 2*lo+1;
    constexpr int off = T_OFFc[P2U_TBLc[p]];
    v2f w = ld2(w2p + P2U_WAc[p] * NC);
    if constexpr (P2U_WBc[p] >= 0) w = w + ld2(w2p + P2U_WBc[p] * NC);
    sfor<dl>([&](auto Kk) {
      constexpr int k = Kk.value;
      v2f v = {0.f, 0.f};
      sfor<d1>([&](auto I) {
        sfor<d2>([&](auto J) {
          constexpr float cgc = CG_ALL.v[off + (I.value * d2 + J.value) * dl + k];
          if constexpr (cgc != 0.0f) {
            constexpr int ia = AOFFc[l1] + I.value, ja = AOFFc[l2] + J.value;
            constexpr int x = ia < ja ? ia : ja, y = ia < ja ? ja : ia;
            v = cfma(cgc, A[x] * A[y], v);
          }
        });
      });
      B[lo + k] = vfma(w, v, B[lo + k]);
    });
  });

  sfor<13>([&](auto CI) {
    constexpr int tk  = CANONc[CI.value];
    constexpr int l1  = K_L1c[tk], l2 = K_L2c[tk], l12 = K_L12c[tk];
    constexpr int d1  = 2*l1+1, d2 = 2*l2+1, d12 = 2*l12+1;
    constexpr int off = T_OFFc[tk];
    v2f tt[d12];
    sfor<d12>([&](auto Kk) {
      constexpr int k = Kk.value;
      v2f v = {0.f, 0.f};
      sfor<d1>([&](auto I) {
        sfor<d2>([&](auto J) {
          constexpr float cgc = CG_ALL.v[off + (I.value * d2 + J.value) * d12 + k];
          if constexpr (cgc != 0.0f) {
            constexpr int ia = AOFFc[l1] + I.value, ja = AOFFc[l2] + J.value;
            constexpr int x = ia < ja ? ia : ja, y = ia < ja ? ja : ia;
            v = cfma(cgc, A[x] * A[y], v);
          }
        });
      });
      tt[k] = v;
    });

    auto consume = [&](auto TK, auto SG) {
      constexpr int tkey = TK.value;
      constexpr float sgn = (float)SG.value;
      constexpr int pcnt = P3_STARTc[tkey + 1] - P3_STARTc[tkey];
      sfor<pcnt>([&](auto PP) {
        constexpr int p  = P3_STARTc[tkey] + PP.value;
        constexpr int l3 = P3_L3c[p], lo = P3_LOc[p];
        constexpr int d3 = 2*l3+1, dl = 2*lo+1;
        constexpr int off2 = T_OFFc[P3_TBLc[p]];
        const v2f w = ld2(w3p + p * NC);
        sfor<dl>([&](auto M) {
          v2f v = {0.f, 0.f};
          sfor<d12>([&](auto Kk) {
            sfor<d3>([&](auto J) {
              constexpr float cgc = sgn * CG_ALL.v[off2 + (Kk.value * d3 + J.value) * dl + M.value];
              if constexpr (cgc != 0.0f)
                v = cfma(cgc, tt[Kk.value] * A[AOFFc[l3] + J.value], v);
            });
          });
          B[lo + M.value] = vfma(w, v, B[lo + M.value]);
        });
      });
    };
    consume(std::integral_constant<int, tk>{}, std::integral_constant<int, 1>{});
    constexpr int td = CONS2c[CI.value];
    if constexpr (td >= 0)
      consume(std::integral_constant<int, td>{},
              std::integral_constant<int, (int)TT_SGNc[td]>{});
  });

  Bws[(size_t)n * NC + c0]     = make_float4(B[0].x, B[1].x, B[2].x, B[3].x);
  Bws[(size_t)n * NC + c0 + 1] = make_float4(B[0].y, B[1].y, B[2].y, B[3].y);
}

// ============================ linear kernel (LDS-staged weights) ===============
// Block 256 thr = 32 f-quads x 8 nodes; 512 blocks (2/CU). Weights staged to
// LDS in two 64-channel phases (2 x 32KB), reused by all 8 nodes. Each thread
// owns the full channel sum for its 4 features x 1 node -> no reduction.
__global__ __launch_bounds__(256) void epb_linear(
    const float4* __restrict__ Bws,    // [N, C]
    const float4* __restrict__ lw0_4,  // [C, F/4]
    const float4* __restrict__ lw1_4,  // [C, F/4]
    float* __restrict__ out)           // [N, F, 4]
{
  __shared__ float4 W0[64 * 32];       // 32 KB  [ch-in-phase][f-quad]
  __shared__ float4 W1[64 * 32];       // 32 KB
  __shared__ float4 Bsh[LTN * NC];     //  8 KB  [node][channel]
  const int t  = threadIdx.x;
  const int nb = blockIdx.x * LTN;

  // stage B tile (coalesced)
  {
    const float4* src = Bws + (size_t)nb * NC;
    sfor<4>([&](auto I) { Bsh[t + 256 * I.value] = src[t + 256 * I.value]; });
  }

  const int q  = t & 31;               // features 4q..4q+3
  const int nl = t >> 5;               // node 0..7

  float4 o0{0,0,0,0}, o1{0,0,0,0}, o2{0,0,0,0}, o3{0,0,0,0};

  #pragma unroll 1
  for (int ph = 0; ph < 2; ++ph) {
    __syncthreads();                   // phase-0 readers done / B staged
    {
      const float4* s0 = lw0_4 + ph * (64 * 32);
      const float4* s1 = lw1_4 + ph * (64 * 32);
      sfor<8>([&](auto I) { W0[t + 256 * I.value] = s0[t + 256 * I.value]; });
      sfor<8>([&](auto I) { W1[t + 256 * I.value] = s1[t + 256 * I.value]; });
    }
    __syncthreads();

    const float4* bp = &Bsh[nl * NC + ph * 64];
    #pragma unroll 4
    for (int ch = 0; ch < 64; ++ch) {
      const float4 wa = W0[ch * 32 + q];   // conflict-free b128
      const float4 wb = W1[ch * 32 + q];
      const float4 b  = bp[ch];            // 2 uniform addrs -> broadcast
      o0.x = fmaf(b.x, wa.x, o0.x); o0.y = fmaf(b.y, wb.x, o0.y);
      o0.z = fmaf(b.z, wb.x, o0.z); o0.w = fmaf(b.w, wb.x, o0.w);
      o1.x = fmaf(b.x, wa.y, o1.x); o1.y = fmaf(b.y, wb.y, o1.y);
      o1.z = fmaf(b.z, wb.y, o1.z); o1.w = fmaf(b.w, wb.y, o1.w);
      o2.x = fmaf(b.x, wa.z, o2.x); o2.y = fmaf(b.y, wb.z, o2.y);
      o2.z = fmaf(b.z, wb.z, o2.z); o2.w = fmaf(b.w, wb.z, o2.w);
      o3.x = fmaf(b.x, wa.w, o3.x); o3.y = fmaf(b.y, wb.w, o3.y);
      o3.z = fmaf(b.z, wb.w, o3.z); o3.w = fmaf(b.w, wb.w, o3.w);
    }
  }

  const float s4 = 0.08838834764831845f;  // 1/sqrt(128)
  float4* o4 = reinterpret_cast<float4*>(out) + (size_t)(nb + nl) * NC + 4 * q;
  o4[0] = make_float4(o0.x*s4, o0.y*s4, o0.z*s4, o0.w*s4);
  o4[1] = make_float4(o1.x*s4, o1.y*s4, o1.z*s4, o1.w*s4);
  o4[2] = make_float4(o2.x*s4, o2.y*s4, o2.z*s4, o2.w*s4);
  o4[3] = make_float4(o3.x*s4, o3.y*s4, o3.z*s4, o3.w*s4);
}

// ------------------------------- launcher --------------------------------------
extern "C" void kernel_launch(void* const* d_in, const int* in_sizes, int n_in,
                              void* d_out, int out_size, void* d_ws, size_t ws_size,
                              hipStream_t stream) {
  const float* nf  = (const float*)d_in[0];
  const float* w1  = (const float*)d_in[1];
  const float* w2  = (const float*)d_in[2];
  const float* w3  = (const float*)d_in[3];
  const float* lw0 = (const float*)d_in[4];
  const float* lw1 = (const float*)d_in[5];
  const int*   spc = (const int*)  d_in[6];
  float* out = (float*)d_out;
  float4* Bws = (float4*)d_ws;   // [N][C] float4 = 8 MB, rebuilt each launch
  (void)ws_size; (void)in_sizes; (void)n_in; (void)out_size;

  hipLaunchKernelGGL(epb_basis, dim3(NN / 4), dim3(256), 0, stream,
                     nf, w1, w2, w3, spc, Bws);
  hipLaunchKernelGGL(epb_linear, dim3(NN / LTN), dim3(256), 0, stream,
                     Bws, (const float4*)lw0, (const float4*)lw1, out);
}